// Round 2
// baseline (561.266 us; speedup 1.0000x reference)
//
#include <hip/hip_runtime.h>

#define NB 32
#define NC 256
#define HC 112
#define WC 112
#define ROI 7
#define KTOT 12544   // NC*ROI*ROI
#define HID 1152
#define NCK 64       // K split count
#define CK 196       // KTOT / NCK
#define BN 128       // columns per proj block
#define FSCALE 0.25f

// ---------------- Kernel 1: ROI align (aligned=True, adaptive grid <= 4) ----
__global__ __launch_bounds__(256) void roi_align_kernel(
    const float* __restrict__ feats, const float* __restrict__ boxes,
    float* __restrict__ xout) {
  int idx = blockIdx.x * 256 + threadIdx.x;   // [0, NB*KTOT)
  int b   = idx / KTOT;
  int rem = idx - b * KTOT;
  int c   = rem / 49;
  int bin = rem - c * 49;
  int py  = bin / 7;
  int px  = bin - py * 7;

  float bx0 = boxes[b * 4 + 0], by0 = boxes[b * 4 + 1];
  float bx1 = boxes[b * 4 + 2], by1 = boxes[b * 4 + 3];
  float sx = bx0 * FSCALE - 0.5f;
  float sy = by0 * FSCALE - 0.5f;
  float ex = bx1 * FSCALE - 0.5f;
  float ey = by1 * FSCALE - 0.5f;
  float roi_w = ex - sx, roi_h = ey - sy;
  float bin_w = roi_w / 7.0f, bin_h = roi_h / 7.0f;
  float gwf = ceilf(roi_w / 7.0f); gwf = fminf(fmaxf(gwf, 1.0f), 4.0f);
  float ghf = ceilf(roi_h / 7.0f); ghf = fminf(fmaxf(ghf, 1.0f), 4.0f);
  int igw = (int)gwf, igh = (int)ghf;

  const float* fp = feats + (size_t)(b * NC + c) * (HC * WC);
  float acc = 0.0f;
  for (int gy = 0; gy < igh; ++gy) {
    float y = sy + (float)py * bin_h + ((float)gy + 0.5f) * bin_h / ghf;
    bool vy = (y >= -1.0f) && (y <= (float)HC);
    float yc = fminf(fmaxf(y, 0.0f), (float)(HC - 1));
    int y0 = (int)floorf(yc); if (y0 > HC - 2) y0 = HC - 2;
    float ly = yc - (float)y0;
    float hy = 1.0f - ly;
    const float* r0 = fp + y0 * WC;
    const float* r1 = r0 + WC;
    for (int gx = 0; gx < igw; ++gx) {
      float x = sx + (float)px * bin_w + ((float)gx + 0.5f) * bin_w / gwf;
      bool vx = (x >= -1.0f) && (x <= (float)WC);
      if (vy && vx) {
        float xc = fminf(fmaxf(x, 0.0f), (float)(WC - 1));
        int x0 = (int)floorf(xc); if (x0 > WC - 2) x0 = WC - 2;
        float lx = xc - (float)x0;
        float hx = 1.0f - lx;
        float v = r0[x0]     * (hy * hx) + r0[x0 + 1] * (hy * lx)
                + r1[x0]     * (ly * hx) + r1[x0 + 1] * (ly * lx);
        acc += v;
      }
    }
  }
  xout[idx] = acc / (ghf * gwf);
}

// ---------------- Kernel 2: split-K projection, atomic accumulation --------
// grid = (HID/BN) * NCK blocks of BN threads. Thread owns one output column n,
// accumulates 32 batch rows over a K-chunk of CK. x-tile broadcast from LDS
// via float4 (ds_read_b128, same-address broadcast => conflict-free).
// Partials accumulated with atomicAdd into hbuf[NB][HID] (147 KB ws instead
// of a 9.4 MB deterministic partials tensor — keeps ws footprint tiny).
__global__ __launch_bounds__(BN) void proj_partial_kernel(
    const float* __restrict__ x, const float* __restrict__ Wp,
    float* __restrict__ hbuf) {
  int nb = blockIdx.x % (HID / BN);
  int ck = blockIdx.x / (HID / BN);
  int n  = nb * BN + threadIdx.x;
  int k0 = ck * CK;

  __shared__ float xs[NB][CK];
  for (int i = threadIdx.x; i < NB * CK; i += BN) {
    int b  = i / CK;
    int kk = i - b * CK;
    xs[b][kk] = x[b * KTOT + k0 + kk];
  }
  __syncthreads();

  float acc[NB];
#pragma unroll
  for (int b = 0; b < NB; ++b) acc[b] = 0.0f;

  const float* wp = Wp + (size_t)k0 * HID + n;
  for (int kk = 0; kk < CK; kk += 4) {
    float w0 = wp[(size_t)(kk + 0) * HID];
    float w1 = wp[(size_t)(kk + 1) * HID];
    float w2 = wp[(size_t)(kk + 2) * HID];
    float w3 = wp[(size_t)(kk + 3) * HID];
#pragma unroll
    for (int b = 0; b < NB; ++b) {
      float4 xv = *(const float4*)&xs[b][kk];
      acc[b] = fmaf(xv.x, w0, acc[b]);
      acc[b] = fmaf(xv.y, w1, acc[b]);
      acc[b] = fmaf(xv.z, w2, acc[b]);
      acc[b] = fmaf(xv.w, w3, acc[b]);
    }
  }

#pragma unroll
  for (int b = 0; b < NB; ++b)
    atomicAdd(&hbuf[(size_t)b * HID + n], acc[b]);
}

// ---------------- Kernel 3: bias + LayerNorm + cls concat -------------------
__global__ __launch_bounds__(256) void finish_kernel(
    const float* __restrict__ hbuf, const float* __restrict__ bias,
    const float* __restrict__ gamma, const float* __restrict__ beta,
    const float* __restrict__ cls, float* __restrict__ out) {
  int b = blockIdx.x;
  __shared__ float hrow[HID];
  __shared__ float rs[4], rq[4];

  float lsum = 0.0f, lsq = 0.0f;
  for (int n = threadIdx.x; n < HID; n += 256) {
    float s = bias[n] + hbuf[(size_t)b * HID + n];
    hrow[n] = s;
    lsum += s;
    lsq  += s * s;
  }
  // wave reduce (64 lanes)
  for (int off = 32; off > 0; off >>= 1) {
    lsum += __shfl_down(lsum, off, 64);
    lsq  += __shfl_down(lsq,  off, 64);
  }
  int wid  = threadIdx.x >> 6;
  int lane = threadIdx.x & 63;
  if (lane == 0) { rs[wid] = lsum; rq[wid] = lsq; }
  __syncthreads();
  if (threadIdx.x == 0) {
    float s = 0.0f, q = 0.0f;
#pragma unroll
    for (int i = 0; i < 4; ++i) { s += rs[i]; q += rq[i]; }
    rs[0] = s; rq[0] = q;
  }
  __syncthreads();
  float mu  = rs[0] * (1.0f / HID);
  float var = rq[0] * (1.0f / HID) - mu * mu;
  float rstd = rsqrtf(var + 1e-5f);

  float* ob = out + (size_t)b * 2 * HID;
  for (int n = threadIdx.x; n < HID; n += 256) {
    ob[n] = cls[n];                                            // row 0: cls token
    ob[HID + n] = gamma[n] * (hrow[n] - mu) * rstd + beta[n];  // row 1: LN token
  }
}

extern "C" void kernel_launch(void* const* d_in, const int* in_sizes, int n_in,
                              void* d_out, int out_size, void* d_ws, size_t ws_size,
                              hipStream_t stream) {
  const float* feats = (const float*)d_in[0];
  const float* boxes = (const float*)d_in[1];
  const float* Wp    = (const float*)d_in[2];
  const float* bias  = (const float*)d_in[3];
  const float* gamma = (const float*)d_in[4];
  const float* beta  = (const float*)d_in[5];
  const float* cls   = (const float*)d_in[6];
  float* out = (float*)d_out;

  float* xbuf = (float*)d_ws;                                   // NB*KTOT floats = 1,605,632 B
  float* hbuf = (float*)((char*)d_ws + (size_t)NB * KTOT * 4);  // NB*HID floats = 147,456 B

  hipMemsetAsync(hbuf, 0, (size_t)NB * HID * 4, stream);        // ws is poisoned 0xAA each call
  roi_align_kernel<<<(NB * KTOT) / 256, 256, 0, stream>>>(feats, boxes, xbuf);
  proj_partial_kernel<<<(HID / BN) * NCK, BN, 0, stream>>>(xbuf, Wp, hbuf);
  finish_kernel<<<NB, 256, 0, stream>>>(hbuf, bias, gamma, beta, cls, out);
}

// Round 3
// 548.701 us; speedup vs baseline: 1.0229x; 1.0229x over previous
//
#include <hip/hip_runtime.h>

#define NB 32
#define NC 256
#define HC 112
#define WC 112
#define KTOT 12544   // NC*7*7
#define HID 1152
#define NCK 112      // K split count
#define CK 112       // KTOT / NCK
#define FSCALE 0.25f

// ---------------- Kernel 1: ROI align (aligned=True, adaptive grid <= 4) ----
// One thread per (b, c, bin). Fixed 4x4 sample grid fully unrolled; adaptive
// grid + range validity folded into tap weights (zero-weight masked samples)
// so all 64 gather loads are independent and in flight together.
__global__ __launch_bounds__(256) void roi_align_kernel(
    const float* __restrict__ feats, const float* __restrict__ boxes,
    float* __restrict__ xout) {
  int idx = blockIdx.x * 256 + threadIdx.x;   // [0, NB*KTOT)
  int b   = idx / KTOT;
  int rem = idx - b * KTOT;
  int c   = rem / 49;
  int bin = rem - c * 49;
  int py  = bin / 7;
  int px  = bin - py * 7;

  float4 bx = ((const float4*)boxes)[b];
  float sx = bx.x * FSCALE - 0.5f;
  float sy = bx.y * FSCALE - 0.5f;
  float roi_w = bx.z * FSCALE - 0.5f - sx;
  float roi_h = bx.w * FSCALE - 0.5f - sy;
  float bin_w = roi_w * (1.0f / 7.0f);
  float bin_h = roi_h * (1.0f / 7.0f);
  float gwf = fminf(fmaxf(ceilf(bin_w), 1.0f), 4.0f);   // ceil(roi_w/7)
  float ghf = fminf(fmaxf(ceilf(bin_h), 1.0f), 4.0f);

  float y_base = sy + (float)py * bin_h;
  float x_base = sx + (float)px * bin_w;
  float step_y = bin_h / ghf, step_x = bin_w / gwf;

  int   ry0[4], rx0[4];
  float why[4], wly[4], whx[4], wlx[4];
#pragma unroll
  for (int g = 0; g < 4; ++g) {
    float y  = y_base + ((float)g + 0.5f) * step_y;
    float vy = ((float)g < ghf && y >= -1.0f && y <= (float)HC) ? 1.0f : 0.0f;
    float yc = fminf(fmaxf(y, 0.0f), (float)(HC - 1));
    int   y0 = (int)yc; if (y0 > HC - 2) y0 = HC - 2;
    float ly = yc - (float)y0;
    ry0[g] = y0; wly[g] = ly * vy; why[g] = (1.0f - ly) * vy;

    float x  = x_base + ((float)g + 0.5f) * step_x;
    float vx = ((float)g < gwf && x >= -1.0f && x <= (float)WC) ? 1.0f : 0.0f;
    float xc = fminf(fmaxf(x, 0.0f), (float)(WC - 1));
    int   x0 = (int)xc; if (x0 > WC - 2) x0 = WC - 2;
    float lx = xc - (float)x0;
    rx0[g] = x0; wlx[g] = lx * vx; whx[g] = (1.0f - lx) * vx;
  }

  const float* fp = feats + (size_t)(b * NC + c) * (HC * WC);
  float acc = 0.0f;
#pragma unroll
  for (int gy = 0; gy < 4; ++gy) {
    const float* r0 = fp + ry0[gy] * WC;
    const float* r1 = r0 + WC;
    float hy = why[gy], ly = wly[gy];
#pragma unroll
    for (int gx = 0; gx < 4; ++gx) {
      int x0 = rx0[gx];
      float f00 = r0[x0], f01 = r0[x0 + 1];
      float f10 = r1[x0], f11 = r1[x0 + 1];
      acc = fmaf(hy * whx[gx], f00, acc);
      acc = fmaf(hy * wlx[gx], f01, acc);
      acc = fmaf(ly * whx[gx], f10, acc);
      acc = fmaf(ly * wlx[gx], f11, acc);
    }
  }
  xout[idx] = acc / (ghf * gwf);
}

// ---------------- Kernel 2: split-K projection, scalar-x + atomic acc -------
// grid = 9 * NCK blocks of 128 threads. Thread owns column n, 32 batch accs.
// x addresses are wave-uniform (no threadIdx dependence) -> compiler emits
// s_load_dwordx4 through the scalar cache; no LDS at all. W reads are fully
// coalesced (consecutive n), streamed exactly once (57.8 MB).
__global__ __launch_bounds__(128) void proj_kernel(
    const float* __restrict__ x, const float* __restrict__ Wp,
    float* __restrict__ hbuf) {
  int nb = blockIdx.x % 9;
  int ck = blockIdx.x / 9;
  int n  = nb * 128 + threadIdx.x;
  int k0 = ck * CK;

  float acc[NB];
#pragma unroll
  for (int b = 0; b < NB; ++b) acc[b] = 0.0f;

  const float* wp = Wp + (size_t)k0 * HID + n;
  const float* xp = x + k0;
  for (int kk = 0; kk < CK; kk += 4) {
    float w0 = wp[0 * HID];
    float w1 = wp[1 * HID];
    float w2 = wp[2 * HID];
    float w3 = wp[3 * HID];
    wp += 4 * HID;
#pragma unroll
    for (int b = 0; b < NB; ++b) {
      float4 xv = *(const float4*)(xp + (size_t)b * KTOT + kk);  // uniform -> s_load
      acc[b] = fmaf(xv.x, w0, acc[b]);
      acc[b] = fmaf(xv.y, w1, acc[b]);
      acc[b] = fmaf(xv.z, w2, acc[b]);
      acc[b] = fmaf(xv.w, w3, acc[b]);
    }
  }

#pragma unroll
  for (int b = 0; b < NB; ++b)
    atomicAdd(&hbuf[(size_t)b * HID + n], acc[b]);
}

// ---------------- Kernel 3: bias + LayerNorm + cls concat -------------------
__global__ __launch_bounds__(256) void finish_kernel(
    const float* __restrict__ hbuf, const float* __restrict__ bias,
    const float* __restrict__ gamma, const float* __restrict__ beta,
    const float* __restrict__ cls, float* __restrict__ out) {
  int b = blockIdx.x;
  __shared__ float hrow[HID];
  __shared__ float rs[4], rq[4];

  float lsum = 0.0f, lsq = 0.0f;
  for (int n = threadIdx.x; n < HID; n += 256) {
    float s = bias[n] + hbuf[(size_t)b * HID + n];
    hrow[n] = s;
    lsum += s;
    lsq  += s * s;
  }
  for (int off = 32; off > 0; off >>= 1) {
    lsum += __shfl_down(lsum, off, 64);
    lsq  += __shfl_down(lsq,  off, 64);
  }
  int wid  = threadIdx.x >> 6;
  int lane = threadIdx.x & 63;
  if (lane == 0) { rs[wid] = lsum; rq[wid] = lsq; }
  __syncthreads();
  if (threadIdx.x == 0) {
    float s = 0.0f, q = 0.0f;
#pragma unroll
    for (int i = 0; i < 4; ++i) { s += rs[i]; q += rq[i]; }
    rs[0] = s; rq[0] = q;
  }
  __syncthreads();
  float mu  = rs[0] * (1.0f / HID);
  float var = rq[0] * (1.0f / HID) - mu * mu;
  float rstd = rsqrtf(var + 1e-5f);

  float* ob = out + (size_t)b * 2 * HID;
  for (int n = threadIdx.x; n < HID; n += 256) {
    ob[n] = cls[n];
    ob[HID + n] = gamma[n] * (hrow[n] - mu) * rstd + beta[n];
  }
}

extern "C" void kernel_launch(void* const* d_in, const int* in_sizes, int n_in,
                              void* d_out, int out_size, void* d_ws, size_t ws_size,
                              hipStream_t stream) {
  const float* feats = (const float*)d_in[0];
  const float* boxes = (const float*)d_in[1];
  const float* Wp    = (const float*)d_in[2];
  const float* bias  = (const float*)d_in[3];
  const float* gamma = (const float*)d_in[4];
  const float* beta  = (const float*)d_in[5];
  const float* cls   = (const float*)d_in[6];
  float* out = (float*)d_out;

  float* xbuf = (float*)d_ws;                                   // NB*KTOT floats = 1,605,632 B
  float* hbuf = (float*)((char*)d_ws + (size_t)NB * KTOT * 4);  // NB*HID floats = 147,456 B

  hipMemsetAsync(hbuf, 0, (size_t)NB * HID * 4, stream);
  roi_align_kernel<<<(NB * KTOT) / 256, 256, 0, stream>>>(feats, boxes, xbuf);
  proj_kernel<<<9 * NCK, 128, 0, stream>>>(xbuf, Wp, hbuf);
  finish_kernel<<<NB, 256, 0, stream>>>(hbuf, bias, gamma, beta, cls, out);
}